// Round 1
// baseline (353.374 us; speedup 1.0000x reference)
//
#include <hip/hip_runtime.h>

typedef _Float16 half8 __attribute__((ext_vector_type(8)));
typedef __attribute__((ext_vector_type(4))) float f32x4;

__device__ __forceinline__ unsigned short f2h(float f) {
    _Float16 h = (_Float16)f;
    return *(unsigned short*)&h;
}
__device__ __forceinline__ float h2f(unsigned short u) {
    _Float16 h = *(_Float16*)&u;
    return (float)h;
}

// ---------- preprocessing: counting sort by key = dst*8 + rel ----------
// hist8 also records each edge's rank within its key (atomicAdd return),
// so scatter needs no second atomic.

__global__ __launch_bounds__(256) void hist8_kernel(
    const int* __restrict__ dst, const int* __restrict__ et,
    int* __restrict__ hist, int* __restrict__ rank, int E)
{
    int e = blockIdx.x * 256 + threadIdx.x;
    if (e < E) rank[e] = atomicAdd(&hist[dst[e] * 8 + et[e]], 1);
}

#define SCAN_TILE 4096
__global__ __launch_bounds__(1024) void scanA_kernel(
    const int* __restrict__ hist, int* __restrict__ bstart,
    int* __restrict__ partial, int nkeys)
{
    __shared__ int wsum[16];
    const int t = threadIdx.x;
    const int lane = t & 63, w = t >> 6;
    const int base = blockIdx.x * SCAN_TILE + t * 4;
    int v[4];
    int s = 0;
#pragma unroll
    for (int i = 0; i < 4; ++i) {
        v[i] = (base + i < nkeys) ? hist[base + i] : 0;
        s += v[i];
    }
    int inc = s;
#pragma unroll
    for (int off = 1; off < 64; off <<= 1) {
        int u = __shfl_up(inc, off);
        if (lane >= off) inc += u;
    }
    if (lane == 63) wsum[w] = inc;
    __syncthreads();
    if (w == 0 && lane < 16) {
        int ws = wsum[lane];
        int winc = ws;
#pragma unroll
        for (int off = 1; off < 16; off <<= 1) {
            int u = __shfl_up(winc, off);
            if (lane >= off) winc += u;
        }
        wsum[lane] = winc - ws;   // exclusive
    }
    __syncthreads();
    int run = wsum[w] + (inc - s);
    int tbase = run;
#pragma unroll
    for (int i = 0; i < 4; ++i) {
        if (base + i < nkeys) bstart[base + i] = run;
        run += v[i];
    }
    if (t == 1023) partial[blockIdx.x] = tbase + s;   // block total
}

__global__ __launch_bounds__(64) void scanB_kernel(
    const int* __restrict__ partial, int* __restrict__ pscan,
    int* __restrict__ bstart_end, int nblk)
{
    const int lane = threadIdx.x;
    int running = 0;
    for (int b = 0; b < nblk; b += 64) {
        int i = b + lane;
        int o = (i < nblk) ? partial[i] : 0;
        int v = o;
#pragma unroll
        for (int off = 1; off < 64; off <<= 1) {
            int u = __shfl_up(v, off);
            if (lane >= off) v += u;
        }
        if (i < nblk) pscan[i] = running + v - o;
        running += __shfl(v, 63);
    }
    if (lane == 0) *bstart_end = running;   // == E
}

__global__ __launch_bounds__(1024) void scanC_kernel(
    int* __restrict__ bstart, const int* __restrict__ pscan, int nkeys)
{
    int i = blockIdx.x * 1024 + threadIdx.x;
    if (i < nkeys) bstart[i] += pscan[i / SCAN_TILE];
}

// scatter: record = { src*9 + rel , f32 scale = 1/cnt(dst,rel) }
// The per-relation mean is thus folded into a single per-edge FMA scale.
__global__ __launch_bounds__(256) void scatter9_kernel(
    const int* __restrict__ src, const int* __restrict__ dst,
    const int* __restrict__ et, const int* __restrict__ rank,
    const int* __restrict__ bstart, uint2* __restrict__ srt, int E)
{
    int e = blockIdx.x * 256 + threadIdx.x;
    if (e < E) {
        int r = et[e];
        int key = dst[e] * 8 + r;
        int b0 = bstart[key];
        int cnt = bstart[key + 1] - b0;            // hist[key], >= 1 here
        float scale = 1.0f / (float)cnt;
        uint2 rec;
        rec.x = (unsigned)(src[e] * 9 + r);
        rec.y = __float_as_uint(scale);
        srt[b0 + rank[e]] = rec;
    }
}

// ---------- W preconversion: f16 image, [global col j][k], stride 72 ----------
// Col layout: j in [0, 9*dout): chunk c=j/dout (0=root, 1..8=W_r), jj=j%dout.

__global__ __launch_bounds__(256) void wprep9_kernel(
    const float* __restrict__ W, const float* __restrict__ root,
    unsigned short* __restrict__ wb, int dout)
{
    int idx = blockIdx.x * 256 + threadIdx.x;
    int total = 9 * dout * 64;
    if (idx >= total) return;
    int j = idx >> 6;          // global col
    int k = idx & 63;
    int c = j / dout, jj = j % dout;
    float f = (c == 0) ? root[k * dout + jj]
                       : W[(size_t)(c - 1) * 64 * dout + k * dout + jj];
    wb[(size_t)j * 72 + k] = f2h(f);
}

// ---------- transform GEMM: T = A(N,64) @ Wcat(64, 9*dout), f16 out ----------
// Block = 128 rows x 288 cols (blockIdx.y picks col-half for dout=64).
// 512 threads = 8 waves; wave w owns rows w*16..w*16+15, all 288 cols.

template <int AF32>
__global__ __launch_bounds__(512, 2) void gemm9_kernel(
    const void* __restrict__ Av,
    const unsigned short* __restrict__ wb,   // (ncols_total, 72) f16
    unsigned short* __restrict__ T,          // (N, trowstride) f16
    int trowstride, int n_nodes)
{
    constexpr int NC = 288;
    constexpr int WSH = NC * 72;             // 20736 halfs = 41.5 KB
    __shared__ __align__(16) unsigned short wt_s[WSH];

    const int t = threadIdx.x;
    const int w = t >> 6, lane = t & 63;
    const int quad = lane >> 4, l16 = lane & 15;
    const int colbase = blockIdx.y * NC;
    const int node0 = blockIdx.x * 128;
    const int row = min(node0 + w * 16 + l16, n_nodes - 1);

    // A fragment: row = l16, k = quad*8(+32)
    half8 a0, a1;
    if (AF32) {
        const float* ar = (const float*)Av + (size_t)row * 64;
        f32x4 x0 = *(const f32x4*)(ar + quad * 8);
        f32x4 x1 = *(const f32x4*)(ar + quad * 8 + 4);
        f32x4 x2 = *(const f32x4*)(ar + 32 + quad * 8);
        f32x4 x3 = *(const f32x4*)(ar + 32 + quad * 8 + 4);
#pragma unroll
        for (int i = 0; i < 4; ++i) {
            a0[i] = (_Float16)x0[i]; a0[i + 4] = (_Float16)x1[i];
            a1[i] = (_Float16)x2[i]; a1[i + 4] = (_Float16)x3[i];
        }
    } else {
        const unsigned short* ar = (const unsigned short*)Av + (size_t)row * 64;
        a0 = *(const half8*)(ar + quad * 8);
        a1 = *(const half8*)(ar + 32 + quad * 8);
    }

    // stage W col-slab
    {
        const uint4* s4 = (const uint4*)(wb + (size_t)colbase * 72);
        uint4* d4 = (uint4*)wt_s;
        for (int i = t; i < WSH / 8; i += 512) d4[i] = s4[i];
    }
    __syncthreads();

    f32x4 d[18];
#pragma unroll
    for (int i = 0; i < 18; ++i) d[i] = {0.f, 0.f, 0.f, 0.f};

#pragma unroll
    for (int jj = 0; jj < 18; ++jj) {
        const int j = jj * 16 + l16;
        half8 b0 = *(const half8*)&wt_s[j * 72 + quad * 8];
        half8 b1 = *(const half8*)&wt_s[j * 72 + 32 + quad * 8];
        d[jj] = __builtin_amdgcn_mfma_f32_16x16x32_f16(a0, b0, d[jj], 0, 0, 0);
        d[jj] = __builtin_amdgcn_mfma_f32_16x16x32_f16(a1, b1, d[jj], 0, 0, 0);
    }

    // C/D layout: col = l16, row-in-tile = quad*4 + r. No bias here (added in agg).
#pragma unroll
    for (int jj = 0; jj < 18; ++jj) {
#pragma unroll
        for (int r = 0; r < 4; ++r) {
            const int node = node0 + w * 16 + quad * 4 + r;
            if (node < n_nodes)
                T[(size_t)node * trowstride + colbase + jj * 16 + l16] = f2h(d[jj][r]);
        }
    }
}

// ---------- aggregation over transformed rows ----------
// T row n = [root_out (DHALF) | rel0 (DHALF) | ... | rel7].
// Edge record q = src*9 + r  ->  gather offset = (q+1)*DHALF + feature.
// acc += T_gather * scale  (scale = 1/cnt folded at sort time).
// DHALF=64: wave = 1 node, lane = feature.  DHALF=32: 2 edges per step
// (lanes 0-31 / 32-63), fold with shfl_xor(32) at the end.

template <int DHALF, int RELU>
__global__ __launch_bounds__(512) void aggT_kernel(
    const unsigned short* __restrict__ T,    // (N, 9*DHALF) f16
    const uint2* __restrict__ srt,
    const int* __restrict__ bstart,
    const float* __restrict__ bias,
    unsigned short* __restrict__ outh,       // DHALF==64: h (N,64) f16
    float* __restrict__ outf,                // DHALF==32: out (N,32) fp32
    int n_nodes)
{
    constexpr int SUB = 64 / DHALF;          // 1 or 2
    const int t = threadIdx.x;
    const int lane = t & 63;
    const int node = blockIdx.x * 8 + (t >> 6);
    if (node >= n_nodes) return;
    const int lf = lane & (DHALF - 1);
    const int sub = (SUB == 2) ? (lane >> 5) : 0;

    const int e0 = bstart[node * 8];
    const int e1 = bstart[node * 8 + 8];

    float acc0 = 0.f, acc1 = 0.f;
    for (int base = e0; base < e1; base += 64) {
        const int blen = min(64, e1 - base);
        uint2 rec; rec.x = 0u; rec.y = 0u;
        if (lane < blen) rec = srt[base + lane];
        int k = 0;
        for (; k + 4 * SUB <= blen; k += 4 * SUB) {
            const int i0 = k + sub;
            const int i1 = k + SUB + sub;
            const int i2 = k + 2 * SUB + sub;
            const int i3 = k + 3 * SUB + sub;
            unsigned q0 = __shfl(rec.x, i0), q1 = __shfl(rec.x, i1);
            unsigned q2 = __shfl(rec.x, i2), q3 = __shfl(rec.x, i3);
            float s0 = __uint_as_float(__shfl(rec.y, i0));
            float s1 = __uint_as_float(__shfl(rec.y, i1));
            float s2 = __uint_as_float(__shfl(rec.y, i2));
            float s3 = __uint_as_float(__shfl(rec.y, i3));
            float v0 = h2f(T[(size_t)(q0 + 1) * DHALF + lf]);
            float v1 = h2f(T[(size_t)(q1 + 1) * DHALF + lf]);
            float v2 = h2f(T[(size_t)(q2 + 1) * DHALF + lf]);
            float v3 = h2f(T[(size_t)(q3 + 1) * DHALF + lf]);
            acc0 = fmaf(v0, s0, acc0);
            acc1 = fmaf(v1, s1, acc1);
            acc0 = fmaf(v2, s2, acc0);
            acc1 = fmaf(v3, s3, acc1);
        }
        for (; k < blen; k += SUB) {
            const int idx = k + sub;               // <= blen <= 63 here
            unsigned q = __shfl(rec.x, idx);
            float s = __uint_as_float(__shfl(rec.y, idx));
            if (SUB == 2 && idx >= blen) s = 0.f;  // lane-guard for odd tails
            float v = h2f(T[(size_t)(q + 1) * DHALF + lf]);
            acc0 = fmaf(v, s, acc0);
        }
    }
    float acc = acc0 + acc1;
    if (SUB == 2) acc += __shfl_xor(acc, 32);

    float o = h2f(T[(size_t)node * (9 * DHALF) + lf]) + bias[lf] + acc;
    if (RELU) o = fmaxf(o, 0.f);
    if (DHALF == 64) {
        outh[(size_t)node * 64 + lane] = f2h(o);
    } else if (lane < 32) {
        outf[(size_t)node * 32 + lane] = o;
    }
}

extern "C" void kernel_launch(void* const* d_in, const int* in_sizes, int n_in,
                              void* d_out, int out_size, void* d_ws, size_t ws_size,
                              hipStream_t stream) {
    const float* x     = (const float*)d_in[0];
    const float* W1    = (const float*)d_in[1];
    const float* root1 = (const float*)d_in[2];
    const float* b1    = (const float*)d_in[3];
    const float* W2    = (const float*)d_in[4];
    const float* root2 = (const float*)d_in[5];
    const float* b2    = (const float*)d_in[6];
    const int*   src   = (const int*)d_in[7];
    const int*   dst   = (const int*)d_in[8];
    const int*   et    = (const int*)d_in[9];

    const int N = in_sizes[0] / 64;
    const int E = in_sizes[7];
    const int KEYS = N * 8;

    char* p = (char*)d_ws;
    auto alloc = [&](size_t bytes) {
        char* r = p;
        p += (bytes + 15) & ~(size_t)15;
        return r;
    };
    uint2* srt          = (uint2*)alloc((size_t)E * 8);
    int* rank           = (int*)alloc((size_t)E * 4);
    int* hist           = (int*)alloc((size_t)KEYS * 4);
    int* bstart         = (int*)alloc((size_t)(KEYS + 1) * 4);
    int* partial        = (int*)alloc(256 * 4);
    int* pscan          = (int*)alloc(256 * 4);
    unsigned short* wb1 = (unsigned short*)alloc((size_t)576 * 72 * 2);
    unsigned short* wb2 = (unsigned short*)alloc((size_t)288 * 72 * 2);
    unsigned short* T   = (unsigned short*)alloc((size_t)N * 576 * 2);  // T1; reused as T2
    unsigned short* h   = (unsigned short*)alloc((size_t)N * 64 * 2);

    hipMemsetAsync(hist, 0, (size_t)KEYS * 4, stream);
    wprep9_kernel<<<(576 * 64 + 255) / 256, 256, 0, stream>>>(W1, root1, wb1, 64);
    wprep9_kernel<<<(288 * 64 + 255) / 256, 256, 0, stream>>>(W2, root2, wb2, 32);
    hist8_kernel<<<(E + 255) / 256, 256, 0, stream>>>(dst, et, hist, rank, E);
    const int nscan = (KEYS + SCAN_TILE - 1) / SCAN_TILE;
    scanA_kernel<<<nscan, 1024, 0, stream>>>(hist, bstart, partial, KEYS);
    scanB_kernel<<<1, 64, 0, stream>>>(partial, pscan, bstart + KEYS, nscan);
    scanC_kernel<<<(KEYS + 1023) / 1024, 1024, 0, stream>>>(bstart, pscan, KEYS);
    scatter9_kernel<<<(E + 255) / 256, 256, 0, stream>>>(src, dst, et, rank, bstart, srt, E);

    // layer 1: T1 = x @ [root1|W1], then aggregate -> h (relu)
    gemm9_kernel<1><<<dim3((N + 127) / 128, 2), 512, 0, stream>>>(x, wb1, T, 576, N);
    aggT_kernel<64, 1><<<(N + 7) / 8, 512, 0, stream>>>(T, srt, bstart, b1, h, nullptr, N);
    // layer 2: T2 = h @ [root2|W2], then aggregate -> out (fp32)
    gemm9_kernel<0><<<dim3((N + 127) / 128, 1), 512, 0, stream>>>(h, wb2, T, 288, N);
    aggT_kernel<32, 0><<<(N + 7) / 8, 512, 0, stream>>>(T, srt, bstart, b2, nullptr,
                                                        (float*)d_out, N);
}